// Round 14
// baseline (97.424 us; speedup 1.0000x reference)
//
#include <hip/hip_runtime.h>

#define IN_DIM   4096
#define OUT_DIM  4096
#define FAN_IN   64
#define ROWS     4
#define NTHREADS 512
#define O_PER_THREAD (OUT_DIM / NTHREADS) // 8
#define MT_BYTES ((size_t)(FAN_IN / 4) * OUT_DIM * 8)   // 512 KB per table

typedef __fp16 v2h __attribute__((ext_vector_type(2)));

// Bijective 8B-block swizzle: spreads LDS bank-pair start groups.
__device__ __forceinline__ int bswz(int m) {
    return (m & ~7) | ((m ^ (m >> 3)) & 7);
}

// pack two f32 -> two f16 (RTZ) in one v_cvt_pkrtz_f16_f32
__device__ __forceinline__ unsigned int pack_f16(float a, float b) {
    v2h h = __builtin_amdgcn_cvt_pkrtz(a, b);
    unsigned int u;
    __builtin_memcpy(&u, &h, sizeof(u));
    return u;
}

// Wave-parallel bank-group scheduler: ONE WAVE PER OUTPUT, zero arrays.
// Lane k owns element k of output o; ballot-derived counts/ranks build a
// bijective slot permutation targeting bank group (s+o)&7 at slot s.
// Mt stores u16 LDS BYTE offsets (bswz(m)<<3), Wt stores f16 weights.
__global__ __launch_bounds__(256)
void schedule_mw(const int* __restrict__ M, const float* __restrict__ W,
                 unsigned short* __restrict__ Mt, __fp16* __restrict__ Wt)
{
    const int o = blockIdx.x * 4 + (threadIdx.x >> 6);   // 4 waves/block
    const int k = threadIdx.x & 63;

    const int   m    = M[(size_t)o * FAN_IN + k];
    const float w    = W[(size_t)o * FAN_IN + k];
    const int   mb   = bswz(m);            // block index, < 4096
    const int   g    = mb & 7;             // bank group

    int cnt[8];
    unsigned long long same = 0;
    #pragma unroll
    for (int h = 0; h < 8; ++h) {
        const unsigned long long b = __ballot(g == h);
        cnt[h] = __popcll(b);
        if (g == h) same = b;
    }
    const unsigned long long ltmask = (k == 0) ? 0ULL : (~0ULL >> (64 - k));
    const int r = __popcll(same & ltmask);         // rank within my group

    int slot;
    if (r < 8) {
        slot = ((g - o) & 7) + 8 * r;              // staggered target slot
    } else {
        int ovr = r - 8;                           // overflow rank
        #pragma unroll
        for (int h = 0; h < 8; ++h)
            if (h < g && cnt[h] > 8) ovr += cnt[h] - 8;
        int hstar = 0, jstar = 0, rem = ovr;
        bool found = false;
        #pragma unroll
        for (int h = 0; h < 8; ++h) {
            const int nh = (cnt[h] < 8) ? (8 - cnt[h]) : 0;
            if (!found && rem < nh) { hstar = h; jstar = cnt[h] + rem; found = true; }
            if (!found) rem -= nh;
        }
        slot = ((hstar - o) & 7) + 8 * jstar;      // fill hole
    }

    // scatter into [trip][o] ushort4 / f16x4 layout
    const int idx = ((slot >> 2) * OUT_DIM + o) * 4 + (slot & 3);
    Mt[idx] = (unsigned short)(mb << 3);           // byte offset, fits u16
    Wt[idx] = (__fp16)w;
}

// v_fma_mix_f32 with BOTH src0 (staged input) and src1 (weight) as f16 halves.
#define FMIX_LL(acc, pk, wp)                                                   \
    asm("v_fma_mix_f32 %0, %1, %2, %0 op_sel:[0,0,0] op_sel_hi:[1,1,0]"        \
        : "+v"(acc) : "v"(pk), "v"(wp))
#define FMIX_HL(acc, pk, wp)                                                   \
    asm("v_fma_mix_f32 %0, %1, %2, %0 op_sel:[1,0,0] op_sel_hi:[1,1,0]"        \
        : "+v"(acc) : "v"(pk), "v"(wp))
#define FMIX_LH(acc, pk, wp)                                                   \
    asm("v_fma_mix_f32 %0, %1, %2, %0 op_sel:[0,1,0] op_sel_hi:[1,1,0]"        \
        : "+v"(acc) : "v"(pk), "v"(wp))
#define FMIX_HH(acc, pk, wp)                                                   \
    asm("v_fma_mix_f32 %0, %1, %2, %0 op_sel:[1,1,0] op_sel_hi:[1,1,0]"        \
        : "+v"(acc) : "v"(pk), "v"(wp))

// 32 KiB LDS + 64-VGPR cap -> 4 blocks/CU = 32 waves/CU (100% occupancy).
template <bool TRANSPOSED>
__global__ __launch_bounds__(NTHREADS, 8)
void ffi_sparse_kernel(const float* __restrict__ inp,
                       const float* __restrict__ W,
                       const int*   __restrict__ M,
                       const float* __restrict__ bias,
                       const uint2* __restrict__ Mt,
                       const uint2* __restrict__ Wt,
                       float* __restrict__ out)
{
    // [col][4 rows] packed f16 pairs: one uint2 (8 B) per column. 32 KiB.
    __shared__ unsigned int lds[IN_DIM * ROWS / 2];

    const int tid = threadIdx.x;
    const int r0  = blockIdx.x * ROWS;

    // ---------------- stage: 4 rows x 4096 cols, f32 -> f16, transpose ----------------
    #pragma unroll
    for (int t = 0; t < 2; ++t) {                // 1024 col-groups / 512 threads
        const int tile = tid + t * NTHREADS;     // 0..1023
        const int c4   = tile << 2;              // column base
        const float* src = inp + (size_t)r0 * IN_DIM + c4;
        const float4 v0 = *(const float4*)(src);
        const float4 v1 = *(const float4*)(src + IN_DIM);
        const float4 v2 = *(const float4*)(src + 2 * IN_DIM);
        const float4 v3 = *(const float4*)(src + 3 * IN_DIM);

        uint2* lds2 = (uint2*)lds;
        lds2[bswz(c4 + 0)] = make_uint2(pack_f16(v0.x, v1.x), pack_f16(v2.x, v3.x));
        lds2[bswz(c4 + 1)] = make_uint2(pack_f16(v0.y, v1.y), pack_f16(v2.y, v3.y));
        lds2[bswz(c4 + 2)] = make_uint2(pack_f16(v0.z, v1.z), pack_f16(v2.z, v3.z));
        lds2[bswz(c4 + 3)] = make_uint2(pack_f16(v0.w, v1.w), pack_f16(v2.w, v3.w));
    }
    __syncthreads();

    const char* __restrict__ ldsb = (const char*)lds;

#define LD64(off) (*(const uint2*)(ldsb + (off)))

    // slot j of a trip: data rows 0..3 in D (2 packed pairs), weight = f16 half of WC
#define CONSUME_WL(D, WP) {                                                    \
        FMIX_LL(acc0, D.x, WP);  FMIX_HL(acc1, D.x, WP);                       \
        FMIX_LL(acc2, D.y, WP);  FMIX_HL(acc3, D.y, WP); }
#define CONSUME_WH(D, WP) {                                                    \
        FMIX_LH(acc0, D.x, WP);  FMIX_HH(acc1, D.x, WP);                       \
        FMIX_LH(acc2, D.y, WP);  FMIX_HH(acc3, D.y, WP); }
#define ISSUE4(D0,D1,D2,D3, MN) {                                              \
        D0 = LD64(MN.x & 0xFFFFu); D1 = LD64(MN.x >> 16);                      \
        D2 = LD64(MN.y & 0xFFFFu); D3 = LD64(MN.y >> 16); }
#define CONS4(D0,D1,D2,D3, WC) {                                               \
        CONSUME_WL(D0, WC.x); CONSUME_WH(D1, WC.x);                            \
        CONSUME_WL(D2, WC.y); CONSUME_WH(D3, WC.y); }
#define MWLD(dm, dw, idx) {                                                    \
        if (TRANSPOSED) {                                                      \
            dm = Mt[(idx) * OUT_DIM + o];                                      \
            dw = Wt[(idx) * OUT_DIM + o];                                      \
        } else {                                                               \
            int4 mr = mp[(idx)];                                               \
            dm.x = (unsigned)(bswz(mr.x) << 3) | ((unsigned)(bswz(mr.y) << 3) << 16); \
            dm.y = (unsigned)(bswz(mr.z) << 3) | ((unsigned)(bswz(mr.w) << 3) << 16); \
            float4 wr = wp[(idx)];                                             \
            dw.x = pack_f16(wr.x, wr.y); dw.y = pack_f16(wr.z, wr.w);          \
        } }

    // Cyclic output mapping -> coalesced stores and coalesced Mt/Wt loads.
    #pragma unroll 1
    for (int i = 0; i < O_PER_THREAD; ++i) {
        const int o = tid + i * NTHREADS;
        const float bv = bias[o];
        float acc0 = bv, acc1 = bv, acc2 = bv, acc3 = bv;

        const int4*   mp = (const int4*)(M + (size_t)o * FAN_IN);   // fallback
        const float4* wp = (const float4*)(W + (size_t)o * FAN_IN);

        // Straight-line 3-stage pipeline, named registers only.
        // Trip c: issue ds-reads for c+1, prefetch Mt/Wt[c+3], consume c.
        uint2  m0, m1, m2, m3;
        uint2  w0, w1, w2, w3;
        uint2  dA0, dA1, dA2, dA3, dB0, dB1, dB2, dB3;

        MWLD(m0, w0, 0);  MWLD(m1, w1, 1);  MWLD(m2, w2, 2);
        ISSUE4(dA0,dA1,dA2,dA3, m0);                                   // trip 0 data

        ISSUE4(dB0,dB1,dB2,dB3, m1);  MWLD(m3,w3, 3);   CONS4(dA0,dA1,dA2,dA3, w0);  // c=0
        ISSUE4(dA0,dA1,dA2,dA3, m2);  MWLD(m0,w0, 4);   CONS4(dB0,dB1,dB2,dB3, w1);  // c=1
        ISSUE4(dB0,dB1,dB2,dB3, m3);  MWLD(m1,w1, 5);   CONS4(dA0,dA1,dA2,dA3, w2);  // c=2
        ISSUE4(dA0,dA1,dA2,dA3, m0);  MWLD(m2,w2, 6);   CONS4(dB0,dB1,dB2,dB3, w3);  // c=3
        ISSUE4(dB0,dB1,dB2,dB3, m1);  MWLD(m3,w3, 7);   CONS4(dA0,dA1,dA2,dA3, w0);  // c=4
        ISSUE4(dA0,dA1,dA2,dA3, m2);  MWLD(m0,w0, 8);   CONS4(dB0,dB1,dB2,dB3, w1);  // c=5
        ISSUE4(dB0,dB1,dB2,dB3, m3);  MWLD(m1,w1, 9);   CONS4(dA0,dA1,dA2,dA3, w2);  // c=6
        ISSUE4(dA0,dA1,dA2,dA3, m0);  MWLD(m2,w2,10);   CONS4(dB0,dB1,dB2,dB3, w3);  // c=7
        ISSUE4(dB0,dB1,dB2,dB3, m1);  MWLD(m3,w3,11);   CONS4(dA0,dA1,dA2,dA3, w0);  // c=8
        ISSUE4(dA0,dA1,dA2,dA3, m2);  MWLD(m0,w0,12);   CONS4(dB0,dB1,dB2,dB3, w1);  // c=9
        ISSUE4(dB0,dB1,dB2,dB3, m3);  MWLD(m1,w1,13);   CONS4(dA0,dA1,dA2,dA3, w2);  // c=10
        ISSUE4(dA0,dA1,dA2,dA3, m0);  MWLD(m2,w2,14);   CONS4(dB0,dB1,dB2,dB3, w3);  // c=11
        ISSUE4(dB0,dB1,dB2,dB3, m1);  MWLD(m3,w3,15);   CONS4(dA0,dA1,dA2,dA3, w0);  // c=12
        ISSUE4(dA0,dA1,dA2,dA3, m2);                    CONS4(dB0,dB1,dB2,dB3, w1);  // c=13
        ISSUE4(dB0,dB1,dB2,dB3, m3);                    CONS4(dA0,dA1,dA2,dA3, w2);  // c=14
                                                        CONS4(dB0,dB1,dB2,dB3, w3);  // c=15

        float* op = out + (size_t)r0 * OUT_DIM + o;
        op[0 * OUT_DIM] = acc0;
        op[1 * OUT_DIM] = acc1;
        op[2 * OUT_DIM] = acc2;
        op[3 * OUT_DIM] = acc3;
    }
#undef CONSUME_WL
#undef CONSUME_WH
#undef ISSUE4
#undef CONS4
#undef MWLD
#undef LD64
}

extern "C" void kernel_launch(void* const* d_in, const int* in_sizes, int n_in,
                              void* d_out, int out_size, void* d_ws, size_t ws_size,
                              hipStream_t stream) {
    const float* inp  = (const float*)d_in[0];
    const float* W    = (const float*)d_in[1];
    const int*   M    = (const int*)d_in[2];
    const float* bias = (const float*)d_in[3];
    float* out = (float*)d_out;

    const int n_rows = in_sizes[0] / IN_DIM;          // 4096
    dim3 grid(n_rows / ROWS), block(NTHREADS);        // 1024 blocks

    const bool use_t = ws_size >= 2 * MT_BYTES;
    if (use_t) {
        unsigned short* Mt = (unsigned short*)d_ws;
        __fp16*         Wt = (__fp16*)((char*)d_ws + MT_BYTES);
        schedule_mw<<<dim3(OUT_DIM / 4), dim3(256), 0, stream>>>(M, W, Mt, Wt);
        ffi_sparse_kernel<true><<<grid, block, 0, stream>>>(inp, W, M, bias,
                                                            (const uint2*)Mt,
                                                            (const uint2*)Wt, out);
    } else {
        ffi_sparse_kernel<false><<<grid, block, 0, stream>>>(inp, W, M, bias,
                                                             (const uint2*)nullptr,
                                                             (const uint2*)nullptr, out);
    }
}

// Round 15
// 88.509 us; speedup vs baseline: 1.1007x; 1.1007x over previous
//
#include <hip/hip_runtime.h>

#define IN_DIM   4096
#define OUT_DIM  4096
#define FAN_IN   64
#define ROWS     8
#define NTHREADS 1024
#define OPT      (OUT_DIM / NTHREADS)   // 4 outputs per thread
#define MT_BYTES ((size_t)(FAN_IN / 4) * OUT_DIM * 16)  // 1 MB per table

typedef __fp16 v2h __attribute__((ext_vector_type(2)));

// Bijective 16B-block swizzle: spreads LDS bank-start groups.
__device__ __forceinline__ int bswz(int m) {
    return (m & ~7) | ((m ^ (m >> 3)) & 7);
}

// pack two f32 -> two f16 (RTZ) in one v_cvt_pkrtz_f16_f32
__device__ __forceinline__ unsigned int pack_f16(float a, float b) {
    v2h h = __builtin_amdgcn_cvt_pkrtz(a, b);
    unsigned int u;
    __builtin_memcpy(&u, &h, sizeof(u));
    return u;
}

// Wave-parallel bank-group scheduler (R13-proven): ONE WAVE PER OUTPUT.
// Bijective slot permutation targets bank group (s+o)&7 at slot s so the main
// kernel's slot-s ds_read_b128 spreads 64 lanes ~8-per-group.
// Mt = pre-swizzled BYTE offsets (bswz(m)<<4), Wt = f32 weights.
__global__ __launch_bounds__(256)
void schedule_mw(const int* __restrict__ M, const float* __restrict__ W,
                 int* __restrict__ Mt, float* __restrict__ Wt)
{
    const int o = blockIdx.x * 4 + (threadIdx.x >> 6);   // 4 waves/block
    const int k = threadIdx.x & 63;

    const int   m    = M[(size_t)o * FAN_IN + k];
    const float w    = W[(size_t)o * FAN_IN + k];
    const int   moff = bswz(m) << 4;
    const int   g    = (moff >> 4) & 7;

    int cnt[8];
    unsigned long long same = 0;
    #pragma unroll
    for (int h = 0; h < 8; ++h) {
        const unsigned long long b = __ballot(g == h);
        cnt[h] = __popcll(b);
        if (g == h) same = b;
    }
    const unsigned long long ltmask = (k == 0) ? 0ULL : (~0ULL >> (64 - k));
    const int r = __popcll(same & ltmask);

    int slot;
    if (r < 8) {
        slot = ((g - o) & 7) + 8 * r;
    } else {
        int ovr = r - 8;
        #pragma unroll
        for (int h = 0; h < 8; ++h)
            if (h < g && cnt[h] > 8) ovr += cnt[h] - 8;
        int hstar = 0, jstar = 0, rem = ovr;
        bool found = false;
        #pragma unroll
        for (int h = 0; h < 8; ++h) {
            const int nh = (cnt[h] < 8) ? (8 - cnt[h]) : 0;
            if (!found && rem < nh) { hstar = h; jstar = cnt[h] + rem; found = true; }
            if (!found) rem -= nh;
        }
        slot = ((hstar - o) & 7) + 8 * jstar;
    }

    const int idx = ((slot >> 2) * OUT_DIM + o) * 4 + (slot & 3);
    Mt[idx] = moff;
    Wt[idx] = w;
}

// v_fma_mix_f32: acc += (f16 half of pk) * w
#define FMAMIX_LO(acc, pk, w)                                                  \
    asm("v_fma_mix_f32 %0, %1, %2, %0 op_sel:[0,0,0] op_sel_hi:[1,0,0]"        \
        : "+v"(acc) : "v"(pk), "v"(w))
#define FMAMIX_HI(acc, pk, w)                                                  \
    asm("v_fma_mix_f32 %0, %1, %2, %0 op_sel:[1,0,0] op_sel_hi:[1,0,0]"        \
        : "+v"(acc) : "v"(pk), "v"(w))

// R13-proven straight-line 3-stage pipeline over 16 trips of 4 k, as an
// inlined function so it can run once per LDS buffer. Named registers only.
template <bool TRANSPOSED>
__device__ __forceinline__ void compute_tile(
    const char* __restrict__ ldsb,
    const int4* __restrict__ Mt, const float4* __restrict__ Wt,
    const float* __restrict__ W, const int* __restrict__ M,
    const float* __restrict__ bias, float* __restrict__ out,
    int r0, int tid)
{
#define LDQ(off) (*(const uint4*)(ldsb + (off)))
#define CONSUME(d, wv) {                                                       \
        FMAMIX_LO(acc0, d.x, wv);  FMAMIX_HI(acc1, d.x, wv);                   \
        FMAMIX_LO(acc2, d.y, wv);  FMAMIX_HI(acc3, d.y, wv);                   \
        FMAMIX_LO(acc4, d.z, wv);  FMAMIX_HI(acc5, d.z, wv);                   \
        FMAMIX_LO(acc6, d.w, wv);  FMAMIX_HI(acc7, d.w, wv);                   \
    }
#define ISSUE4(D0,D1,D2,D3, MN) {                                              \
        D0 = LDQ(MN.x); D1 = LDQ(MN.y); D2 = LDQ(MN.z); D3 = LDQ(MN.w); }
#define CONS4(D0,D1,D2,D3, WC) {                                               \
        CONSUME(D0, WC.x); CONSUME(D1, WC.y);                                  \
        CONSUME(D2, WC.z); CONSUME(D3, WC.w); }
#define MWLD(dm, dw, idx) {                                                    \
        if (TRANSPOSED) {                                                      \
            dm = Mt[(idx) * OUT_DIM + o];                                      \
            dw = Wt[(idx) * OUT_DIM + o];                                      \
        } else {                                                               \
            int4 mr = mp[(idx)];                                               \
            mr.x = bswz(mr.x) << 4; mr.y = bswz(mr.y) << 4;                    \
            mr.z = bswz(mr.z) << 4; mr.w = bswz(mr.w) << 4;                    \
            dm = mr; dw = wp[(idx)];                                           \
        } }

    #pragma unroll 1
    for (int i = 0; i < OPT; ++i) {
        const int o = tid + i * NTHREADS;
        const float bv = bias[o];
        float acc0 = bv, acc1 = bv, acc2 = bv, acc3 = bv;
        float acc4 = bv, acc5 = bv, acc6 = bv, acc7 = bv;

        const int4*   mp = (const int4*)(M + (size_t)o * FAN_IN);   // fallback
        const float4* wp = (const float4*)(W + (size_t)o * FAN_IN);

        int4   m0, m1, m2, m3;
        float4 w0, w1, w2, w3;
        uint4  dA0, dA1, dA2, dA3, dB0, dB1, dB2, dB3;

        MWLD(m0, w0, 0);  MWLD(m1, w1, 1);  MWLD(m2, w2, 2);
        ISSUE4(dA0,dA1,dA2,dA3, m0);

        ISSUE4(dB0,dB1,dB2,dB3, m1);  MWLD(m3,w3, 3);   CONS4(dA0,dA1,dA2,dA3, w0);
        ISSUE4(dA0,dA1,dA2,dA3, m2);  MWLD(m0,w0, 4);   CONS4(dB0,dB1,dB2,dB3, w1);
        ISSUE4(dB0,dB1,dB2,dB3, m3);  MWLD(m1,w1, 5);   CONS4(dA0,dA1,dA2,dA3, w2);
        ISSUE4(dA0,dA1,dA2,dA3, m0);  MWLD(m2,w2, 6);   CONS4(dB0,dB1,dB2,dB3, w3);
        ISSUE4(dB0,dB1,dB2,dB3, m1);  MWLD(m3,w3, 7);   CONS4(dA0,dA1,dA2,dA3, w0);
        ISSUE4(dA0,dA1,dA2,dA3, m2);  MWLD(m0,w0, 8);   CONS4(dB0,dB1,dB2,dB3, w1);
        ISSUE4(dB0,dB1,dB2,dB3, m3);  MWLD(m1,w1, 9);   CONS4(dA0,dA1,dA2,dA3, w2);
        ISSUE4(dA0,dA1,dA2,dA3, m0);  MWLD(m2,w2,10);   CONS4(dB0,dB1,dB2,dB3, w3);
        ISSUE4(dB0,dB1,dB2,dB3, m1);  MWLD(m3,w3,11);   CONS4(dA0,dA1,dA2,dA3, w0);
        ISSUE4(dA0,dA1,dA2,dA3, m2);  MWLD(m0,w0,12);   CONS4(dB0,dB1,dB2,dB3, w1);
        ISSUE4(dB0,dB1,dB2,dB3, m3);  MWLD(m1,w1,13);   CONS4(dA0,dA1,dA2,dA3, w2);
        ISSUE4(dA0,dA1,dA2,dA3, m0);  MWLD(m2,w2,14);   CONS4(dB0,dB1,dB2,dB3, w3);
        ISSUE4(dB0,dB1,dB2,dB3, m1);  MWLD(m3,w3,15);   CONS4(dA0,dA1,dA2,dA3, w0);
        ISSUE4(dA0,dA1,dA2,dA3, m2);                    CONS4(dB0,dB1,dB2,dB3, w1);
        ISSUE4(dB0,dB1,dB2,dB3, m3);                    CONS4(dA0,dA1,dA2,dA3, w2);
                                                        CONS4(dB0,dB1,dB2,dB3, w3);

        float* op = out + (size_t)r0 * OUT_DIM + o;
        op[0 * OUT_DIM] = acc0;
        op[1 * OUT_DIM] = acc1;
        op[2 * OUT_DIM] = acc2;
        op[3 * OUT_DIM] = acc3;
        op[4 * OUT_DIM] = acc4;
        op[5 * OUT_DIM] = acc5;
        op[6 * OUT_DIM] = acc6;
        op[7 * OUT_DIM] = acc7;
    }
#undef CONSUME
#undef ISSUE4
#undef CONS4
#undef MWLD
#undef LDQ
}

// Persistent 2-tile block: 1024 threads, 128 KiB LDS double-buffer,
// 1 block/CU (16 waves). Tile-B global loads issue BEFORE tile-A compute
// (T14 async-stage split): HBM latency hides under the gather phase.
template <bool TRANSPOSED>
__global__ __launch_bounds__(NTHREADS, 4)
void ffi_sparse_kernel(const float* __restrict__ inp,
                       const float* __restrict__ W,
                       const int*   __restrict__ M,
                       const float* __restrict__ bias,
                       const int4*  __restrict__ Mt,
                       const float4* __restrict__ Wt,
                       float* __restrict__ out)
{
    __shared__ unsigned int lds[2][IN_DIM * ROWS / 2];   // 2 x 64 KiB

    const int tid = threadIdx.x;
    const int r0a = blockIdx.x * ROWS;                   // tiles 0..255
    const int r0b = (blockIdx.x + gridDim.x) * ROWS;     // tiles 256..511
    const int c4  = tid << 2;                            // column base 0..4092

    // ---- stage tile A -> buf0 (direct) ----
    #pragma unroll
    for (int t = 0; t < 2; ++t) {
        const float* src = inp + (size_t)(r0a + t * 4) * IN_DIM + c4;
        const float4 v0 = *(const float4*)(src);
        const float4 v1 = *(const float4*)(src + IN_DIM);
        const float4 v2 = *(const float4*)(src + 2 * IN_DIM);
        const float4 v3 = *(const float4*)(src + 3 * IN_DIM);
        unsigned int* p;
        p = &lds[0][0] + bswz(c4 + 0) * 4 + t * 2;
        *(uint2*)p = make_uint2(pack_f16(v0.x, v1.x), pack_f16(v2.x, v3.x));
        p = &lds[0][0] + bswz(c4 + 1) * 4 + t * 2;
        *(uint2*)p = make_uint2(pack_f16(v0.y, v1.y), pack_f16(v2.y, v3.y));
        p = &lds[0][0] + bswz(c4 + 2) * 4 + t * 2;
        *(uint2*)p = make_uint2(pack_f16(v0.z, v1.z), pack_f16(v2.z, v3.z));
        p = &lds[0][0] + bswz(c4 + 3) * 4 + t * 2;
        *(uint2*)p = make_uint2(pack_f16(v0.w, v1.w), pack_f16(v2.w, v3.w));
    }
    __syncthreads();

    // ---- issue tile B global loads early (named regs; consumed after A) ----
    const float* sB0 = inp + (size_t)(r0b) * IN_DIM + c4;
    const float* sB1 = inp + (size_t)(r0b + 4) * IN_DIM + c4;
    const float4 qa0 = *(const float4*)(sB0);
    const float4 qa1 = *(const float4*)(sB0 + IN_DIM);
    const float4 qa2 = *(const float4*)(sB0 + 2 * IN_DIM);
    const float4 qa3 = *(const float4*)(sB0 + 3 * IN_DIM);
    const float4 qb0 = *(const float4*)(sB1);
    const float4 qb1 = *(const float4*)(sB1 + IN_DIM);
    const float4 qb2 = *(const float4*)(sB1 + 2 * IN_DIM);
    const float4 qb3 = *(const float4*)(sB1 + 3 * IN_DIM);

    // ---- compute tile A from buf0 (LDS pipe saturated; B loads in flight) ----
    compute_tile<TRANSPOSED>((const char*)&lds[0][0], Mt, Wt, W, M, bias, out, r0a, tid);

    // ---- write tile B -> buf1 (disjoint from buf0: no pre-sync needed) ----
    {
        unsigned int* b1 = &lds[1][0];
        unsigned int* p;
        p = b1 + bswz(c4 + 0) * 4;
        *(uint2*)p = make_uint2(pack_f16(qa0.x, qa1.x), pack_f16(qa2.x, qa3.x));
        p = b1 + bswz(c4 + 1) * 4;
        *(uint2*)p = make_uint2(pack_f16(qa0.y, qa1.y), pack_f16(qa2.y, qa3.y));
        p = b1 + bswz(c4 + 2) * 4;
        *(uint2*)p = make_uint2(pack_f16(qa0.z, qa1.z), pack_f16(qa2.z, qa3.z));
        p = b1 + bswz(c4 + 3) * 4;
        *(uint2*)p = make_uint2(pack_f16(qa0.w, qa1.w), pack_f16(qa2.w, qa3.w));
        p = b1 + bswz(c4 + 0) * 4 + 2;
        *(uint2*)p = make_uint2(pack_f16(qb0.x, qb1.x), pack_f16(qb2.x, qb3.x));
        p = b1 + bswz(c4 + 1) * 4 + 2;
        *(uint2*)p = make_uint2(pack_f16(qb0.y, qb1.y), pack_f16(qb2.y, qb3.y));
        p = b1 + bswz(c4 + 2) * 4 + 2;
        *(uint2*)p = make_uint2(pack_f16(qb0.z, qb1.z), pack_f16(qb2.z, qb3.z));
        p = b1 + bswz(c4 + 3) * 4 + 2;
        *(uint2*)p = make_uint2(pack_f16(qb0.w, qb1.w), pack_f16(qb2.w, qb3.w));
    }
    __syncthreads();

    // ---- compute tile B from buf1 ----
    compute_tile<TRANSPOSED>((const char*)&lds[1][0], Mt, Wt, W, M, bias, out, r0b, tid);
}

extern "C" void kernel_launch(void* const* d_in, const int* in_sizes, int n_in,
                              void* d_out, int out_size, void* d_ws, size_t ws_size,
                              hipStream_t stream) {
    const float* inp  = (const float*)d_in[0];
    const float* W    = (const float*)d_in[1];
    const int*   M    = (const int*)d_in[2];
    const float* bias = (const float*)d_in[3];
    float* out = (float*)d_out;

    const int n_rows = in_sizes[0] / IN_DIM;              // 4096
    dim3 grid(n_rows / (ROWS * 2)), block(NTHREADS);      // 256 blocks x 1024

    const bool use_t = ws_size >= 2 * MT_BYTES;
    if (use_t) {
        int*   Mt = (int*)d_ws;
        float* Wt = (float*)((char*)d_ws + MT_BYTES);
        schedule_mw<<<dim3(OUT_DIM / 4), dim3(256), 0, stream>>>(M, W, Mt, Wt);
        ffi_sparse_kernel<true><<<grid, block, 0, stream>>>(inp, W, M, bias,
                                                            (const int4*)Mt,
                                                            (const float4*)Wt, out);
    } else {
        ffi_sparse_kernel<false><<<grid, block, 0, stream>>>(inp, W, M, bias,
                                                             (const int4*)nullptr,
                                                             (const float4*)nullptr, out);
    }
}

// Round 16
// 71.569 us; speedup vs baseline: 1.3613x; 1.2367x over previous
//
#include <hip/hip_runtime.h>

#define IN_DIM   4096
#define OUT_DIM  4096
#define FAN_IN   64
#define ROWS     8
#define NTHREADS 512
#define O_PER_THREAD (OUT_DIM / NTHREADS) // 8
#define MT_BYTES ((size_t)(FAN_IN / 4) * OUT_DIM * 16)  // 1 MB per table

typedef __fp16 v2h __attribute__((ext_vector_type(2)));

// Bijective 16B-block swizzle: spreads LDS bank-start groups.
__device__ __forceinline__ int bswz(int m) {
    return (m & ~7) | ((m ^ (m >> 3)) & 7);
}

// pack two f32 -> two f16 (RTZ) in one v_cvt_pkrtz_f16_f32
__device__ __forceinline__ unsigned int pack_f16(float a, float b) {
    v2h h = __builtin_amdgcn_cvt_pkrtz(a, b);
    unsigned int u;
    __builtin_memcpy(&u, &h, sizeof(u));
    return u;
}

// Wave-parallel bank-group scheduler: ONE WAVE PER OUTPUT, zero arrays.
// Bijective slot permutation targets bank group (s+o)&7 at slot s so the main
// kernel's slot-s ds_read_b128 spreads its 64 lanes ~8 per bank group.
__global__ __launch_bounds__(256)
void schedule_mw(const int* __restrict__ M, const float* __restrict__ W,
                 int* __restrict__ Mt, float* __restrict__ Wt)
{
    const int o = blockIdx.x * 4 + (threadIdx.x >> 6);   // 4 waves/block
    const int k = threadIdx.x & 63;

    const int   m    = M[(size_t)o * FAN_IN + k];
    const float w    = W[(size_t)o * FAN_IN + k];
    const int   moff = bswz(m) << 4;       // pre-swizzled byte offset
    const int   g    = (moff >> 4) & 7;    // bank group

    int cnt[8];
    unsigned long long same = 0;
    #pragma unroll
    for (int h = 0; h < 8; ++h) {
        const unsigned long long b = __ballot(g == h);
        cnt[h] = __popcll(b);
        if (g == h) same = b;
    }
    const unsigned long long ltmask = (k == 0) ? 0ULL : (~0ULL >> (64 - k));
    const int r = __popcll(same & ltmask);         // rank within my group

    int slot;
    if (r < 8) {
        slot = ((g - o) & 7) + 8 * r;              // staggered target slot
    } else {
        int ovr = r - 8;                           // overflow rank
        #pragma unroll
        for (int h = 0; h < 8; ++h)
            if (h < g && cnt[h] > 8) ovr += cnt[h] - 8;
        int hstar = 0, jstar = 0, rem = ovr;
        bool found = false;
        #pragma unroll
        for (int h = 0; h < 8; ++h) {
            const int nh = (cnt[h] < 8) ? (8 - cnt[h]) : 0;
            if (!found && rem < nh) { hstar = h; jstar = cnt[h] + rem; found = true; }
            if (!found) rem -= nh;
        }
        slot = ((hstar - o) & 7) + 8 * jstar;      // fill hole
    }

    const int idx = ((slot >> 2) * OUT_DIM + o) * 4 + (slot & 3);
    Mt[idx] = moff;
    Wt[idx] = w;
}

// v_fma_mix_f32: acc += (f16 half of pk) * w   (f16->f32 convert exact, fma in f32)
#define FMAMIX_LO(acc, pk, w)                                                  \
    asm("v_fma_mix_f32 %0, %1, %2, %0 op_sel:[0,0,0] op_sel_hi:[1,0,0]"        \
        : "+v"(acc) : "v"(pk), "v"(w))
#define FMAMIX_HI(acc, pk, w)                                                  \
    asm("v_fma_mix_f32 %0, %1, %2, %0 op_sel:[1,0,0] op_sel_hi:[1,0,0]"        \
        : "+v"(acc) : "v"(pk), "v"(w))

// 64 KiB LDS -> 2 blocks/CU (LDS-capped, 16 waves/CU). VGPR cap 128.
template <bool TRANSPOSED>
__global__ __launch_bounds__(NTHREADS, 4)
void ffi_sparse_kernel(const float* __restrict__ inp,
                       const float* __restrict__ W,
                       const int*   __restrict__ M,
                       const float* __restrict__ bias,
                       const int4*  __restrict__ Mt,
                       const float4* __restrict__ Wt,
                       float* __restrict__ out)
{
    // [col][8 rows] packed f16 pairs: one uint4 (16 B) per column. 64 KiB.
    __shared__ unsigned int lds[IN_DIM * ROWS / 2];

    const int tid = threadIdx.x;
    const int r0  = blockIdx.x * ROWS;

    // ---------------- stage: 8 rows x 4096 cols, f32 -> f16, transpose --------------
    // Each thread owns whole columns: load 8 rows x 4 cols (8x float4), write each
    // column as ONE ds_write_b128 (same byte layout compute reads: pair j = rows 2j,2j+1).
    #pragma unroll
    for (int t = 0; t < 2; ++t) {                // 1024 column-quads / 512 threads
        const int c4 = (tid + t * NTHREADS) << 2;
        const float* src = inp + (size_t)r0 * IN_DIM + c4;
        const float4 v0 = *(const float4*)(src);
        const float4 v1 = *(const float4*)(src + IN_DIM);
        const float4 v2 = *(const float4*)(src + 2 * IN_DIM);
        const float4 v3 = *(const float4*)(src + 3 * IN_DIM);
        const float4 v4 = *(const float4*)(src + 4 * IN_DIM);
        const float4 v5 = *(const float4*)(src + 5 * IN_DIM);
        const float4 v6 = *(const float4*)(src + 6 * IN_DIM);
        const float4 v7 = *(const float4*)(src + 7 * IN_DIM);

        uint4* q = (uint4*)lds;
        q[bswz(c4 + 0)] = make_uint4(pack_f16(v0.x, v1.x), pack_f16(v2.x, v3.x),
                                     pack_f16(v4.x, v5.x), pack_f16(v6.x, v7.x));
        q[bswz(c4 + 1)] = make_uint4(pack_f16(v0.y, v1.y), pack_f16(v2.y, v3.y),
                                     pack_f16(v4.y, v5.y), pack_f16(v6.y, v7.y));
        q[bswz(c4 + 2)] = make_uint4(pack_f16(v0.z, v1.z), pack_f16(v2.z, v3.z),
                                     pack_f16(v4.z, v5.z), pack_f16(v6.z, v7.z));
        q[bswz(c4 + 3)] = make_uint4(pack_f16(v0.w, v1.w), pack_f16(v2.w, v3.w),
                                     pack_f16(v4.w, v5.w), pack_f16(v6.w, v7.w));
    }
    __syncthreads();

    const char* __restrict__ ldsb = (const char*)lds;

#define LDQ(off) (*(const uint4*)(ldsb + (off)))

    // 8 x v_fma_mix_f32 per (o,k): zero unpack instructions.
#define CONSUME(d, wv) {                                                       \
        FMAMIX_LO(acc0, d.x, wv);  FMAMIX_HI(acc1, d.x, wv);                   \
        FMAMIX_LO(acc2, d.y, wv);  FMAMIX_HI(acc3, d.y, wv);                   \
        FMAMIX_LO(acc4, d.z, wv);  FMAMIX_HI(acc5, d.z, wv);                   \
        FMAMIX_LO(acc6, d.w, wv);  FMAMIX_HI(acc7, d.w, wv);                   \
    }
#define ISSUE4(D0,D1,D2,D3, MN) {                                              \
        D0 = LDQ(MN.x); D1 = LDQ(MN.y); D2 = LDQ(MN.z); D3 = LDQ(MN.w); }
#define CONS4(D0,D1,D2,D3, WC) {                                               \
        CONSUME(D0, WC.x); CONSUME(D1, WC.y);                                  \
        CONSUME(D2, WC.z); CONSUME(D3, WC.w); }
#define MWLD(dm, dw, idx) {                                                    \
        if (TRANSPOSED) {                                                      \
            dm = Mt[(idx) * OUT_DIM + o];                                      \
            dw = Wt[(idx) * OUT_DIM + o];                                      \
        } else {                                                               \
            int4 mr = mp[(idx)];                                               \
            mr.x = bswz(mr.x) << 4; mr.y = bswz(mr.y) << 4;                    \
            mr.z = bswz(mr.z) << 4; mr.w = bswz(mr.w) << 4;                    \
            dm = mr; dw = wp[(idx)];                                           \
        } }

    // Cyclic output mapping -> coalesced stores and coalesced Mt/Wt loads.
    #pragma unroll 1
    for (int i = 0; i < O_PER_THREAD; ++i) {
        const int o = tid + i * NTHREADS;
        const float bv = bias[o];
        float acc0 = bv, acc1 = bv, acc2 = bv, acc3 = bv;
        float acc4 = bv, acc5 = bv, acc6 = bv, acc7 = bv;

        const int4*   mp = (const int4*)(M + (size_t)o * FAN_IN);   // fallback
        const float4* wp = (const float4*)(W + (size_t)o * FAN_IN);

        // Straight-line 3-stage pipeline, named registers only (no arrays ->
        // no possible scratch). Trip c: issue ds-reads for c+1, prefetch
        // Mt/Wt[c+3], consume c. Buffers alternate dA/dB; m/w are a 4-ring.
        int4   m0, m1, m2, m3;
        float4 w0, w1, w2, w3;
        uint4  dA0, dA1, dA2, dA3, dB0, dB1, dB2, dB3;

        MWLD(m0, w0, 0);  MWLD(m1, w1, 1);  MWLD(m2, w2, 2);
        ISSUE4(dA0,dA1,dA2,dA3, m0);                                   // trip 0 data

        ISSUE4(dB0,dB1,dB2,dB3, m1);  MWLD(m3,w3, 3);   CONS4(dA0,dA1,dA2,dA3, w0);  // c=0
        ISSUE4(dA0,dA1,dA2,dA3, m2);  MWLD(m0,w0, 4);   CONS4(dB0,dB1,dB2,dB3, w1);  // c=1
        ISSUE4(dB0,dB1,dB2,dB3, m3);  MWLD(m1,w1, 5);   CONS4(dA0,dA1,dA2,dA3, w2);  // c=2
        ISSUE4(dA0,dA1,dA2,dA3, m0);  MWLD(m2,w2, 6);   CONS4(dB0,dB1,dB2,dB3, w3);  // c=3
        ISSUE4(dB0,dB1,dB2,dB3, m1);  MWLD(m3,w3, 7);   CONS4(dA0,dA1,dA2,dA3, w0);  // c=4
        ISSUE4(dA0,dA1,dA2,dA3, m2);  MWLD(m0,w0, 8);   CONS4(dB0,dB1,dB2,dB3, w1);  // c=5
        ISSUE4(dB0,dB1,dB2,dB3, m3);  MWLD(m1,w1, 9);   CONS4(dA0,dA1,dA2,dA3, w2);  // c=6
        ISSUE4(dA0,dA1,dA2,dA3, m0);  MWLD(m2,w2,10);   CONS4(dB0,dB1,dB2,dB3, w3);  // c=7
        ISSUE4(dB0,dB1,dB2,dB3, m1);  MWLD(m3,w3,11);   CONS4(dA0,dA1,dA2,dA3, w0);  // c=8
        ISSUE4(dA0,dA1,dA2,dA3, m2);  MWLD(m0,w0,12);   CONS4(dB0,dB1,dB2,dB3, w1);  // c=9
        ISSUE4(dB0,dB1,dB2,dB3, m3);  MWLD(m1,w1,13);   CONS4(dA0,dA1,dA2,dA3, w2);  // c=10
        ISSUE4(dA0,dA1,dA2,dA3, m0);  MWLD(m2,w2,14);   CONS4(dB0,dB1,dB2,dB3, w3);  // c=11
        ISSUE4(dB0,dB1,dB2,dB3, m1);  MWLD(m3,w3,15);   CONS4(dA0,dA1,dA2,dA3, w0);  // c=12
        ISSUE4(dA0,dA1,dA2,dA3, m2);                    CONS4(dB0,dB1,dB2,dB3, w1);  // c=13
        ISSUE4(dB0,dB1,dB2,dB3, m3);                    CONS4(dA0,dA1,dA2,dA3, w2);  // c=14
                                                        CONS4(dB0,dB1,dB2,dB3, w3);  // c=15

        float* op = out + (size_t)r0 * OUT_DIM + o;
        op[0 * OUT_DIM] = acc0;
        op[1 * OUT_DIM] = acc1;
        op[2 * OUT_DIM] = acc2;
        op[3 * OUT_DIM] = acc3;
        op[4 * OUT_DIM] = acc4;
        op[5 * OUT_DIM] = acc5;
        op[6 * OUT_DIM] = acc6;
        op[7 * OUT_DIM] = acc7;
    }
#undef CONSUME
#undef ISSUE4
#undef CONS4
#undef MWLD
#undef LDQ
}

extern "C" void kernel_launch(void* const* d_in, const int* in_sizes, int n_in,
                              void* d_out, int out_size, void* d_ws, size_t ws_size,
                              hipStream_t stream) {
    const float* inp  = (const float*)d_in[0];
    const float* W    = (const float*)d_in[1];
    const int*   M    = (const int*)d_in[2];
    const float* bias = (const float*)d_in[3];
    float* out = (float*)d_out;

    const int n_rows = in_sizes[0] / IN_DIM;          // 4096
    dim3 grid(n_rows / ROWS), block(NTHREADS);        // 512 blocks x 512

    const bool use_t = ws_size >= 2 * MT_BYTES;
    if (use_t) {
        int*   Mt = (int*)d_ws;
        float* Wt = (float*)((char*)d_ws + MT_BYTES);
        schedule_mw<<<dim3(OUT_DIM / 4), dim3(256), 0, stream>>>(M, W, Mt, Wt);
        ffi_sparse_kernel<true><<<grid, block, 0, stream>>>(inp, W, M, bias,
                                                            (const int4*)Mt,
                                                            (const float4*)Wt, out);
    } else {
        ffi_sparse_kernel<false><<<grid, block, 0, stream>>>(inp, W, M, bias,
                                                             (const int4*)nullptr,
                                                             (const float4*)nullptr, out);
    }
}